// Round 5
// baseline (262.876 us; speedup 1.0000x reference)
//
#include <hip/hip_runtime.h>
#include <stdint.h>

#define T_STEPS 256
#define F_IN 64
#define L2E 1.44269504f

typedef __bf16 bf16x8 __attribute__((ext_vector_type(8)));
typedef float f32x4 __attribute__((ext_vector_type(4)));
typedef uint32_t u32;
typedef uint32_t u32x2 __attribute__((ext_vector_type(2)));
typedef uint32_t u32x4 __attribute__((ext_vector_type(4)));

#define GLDS16(gp, lp)                                                         \
    __builtin_amdgcn_global_load_lds(                                          \
        (const __attribute__((address_space(1))) unsigned int*)(gp),           \
        (__attribute__((address_space(3))) unsigned int*)(lp), 16, 0, 0)

static __device__ __forceinline__ u32 pk2(float lo, float hi) {
    unsigned short a = __builtin_bit_cast(unsigned short, (__bf16)lo);
    unsigned short b = __builtin_bit_cast(unsigned short, (__bf16)hi);
    return (u32)a | ((u32)b << 16);
}

// Same structure as round 4 (2 waves per 16-row tile, split by hidden unit,
// one barrier/step, dbuf h in LDS), EXCEPT x staging is batched: one batch of
// 4 steps is issued every 4 steps as per-row-contiguous 512B bursts per wave
// (1KB per row per batch across the 2 waves) into an 8-slot ring. This turns
// the 256B-per-DRAM-page-visit pattern (4 activations/KB) into one
// activation/KB.
__global__ __launch_bounds__(128, 2)
void lstm_fused(const float* __restrict__ x,
                const float* __restrict__ Wl,   // [96][128]
                const float* __restrict__ bl,   // [128]
                const float* __restrict__ Wd,   // [32]
                const float* __restrict__ bd,   // [1]
                float* __restrict__ out)        // [B]
{
    __shared__ __align__(16) float  xs[8][1024];   // 32 KB x ring (8 step-slots)
    __shared__ __align__(16) __bf16 hf[2][64][8];  // h in MFMA B-frag layout, dbuf

    const int lane = threadIdx.x & 63;
    const int wid  = threadIdx.x >> 6;             // unit-half owner
    const int cl   = lane & 15;
    const int g4   = lane >> 4;
    const int rowBase = blockIdx.x * 16;

    // ---- this wave's 12 W^T A-fragments (q = 2*qi + wid) ----
    bf16x8 wfrag[3][4];
#pragma unroll
    for (int kc = 0; kc < 3; ++kc) {
#pragma unroll
        for (int qi = 0; qi < 4; ++qi) {
            bf16x8 v;
#pragma unroll
            for (int j = 0; j < 8; ++j)
                v[j] = (__bf16)Wl[(kc * 32 + g4 * 8 + j) * 128 + (2 * qi + wid) * 16 + cl];
            wfrag[kc][qi] = v;
        }
    }

    // ---- folded bias constants; this lane's units u = wid*16 + g4*4 + r ----
    float KI[4], KJ[4], KF[4], KO[4];
    {
        const int u0 = wid * 16 + g4 * 4;
#pragma unroll
        for (int r = 0; r < 4; ++r) {
            KI[r] = -L2E        *  bl[      u0 + r];
            KJ[r] = -2.0f * L2E *  bl[ 32 + u0 + r];
            KF[r] = -L2E        * (bl[ 64 + u0 + r] + 1.0f);
            KO[r] = -L2E        *  bl[ 96 + u0 + r];
        }
    }
    const float bd0 = bd[0];
    const f32x4 wdA = *(const f32x4*)(Wd + g4 * 8);
    const f32x4 wdB = *(const f32x4*)(Wd + g4 * 8 + 4);

    // per-lane pre-swizzled global base (row = lane>>2, 16B chunk (lane&3)^((lane>>3)&3))
    const float* gbase = x + (size_t)(rowBase + (lane >> 2)) * (size_t)(T_STEPS * F_IN)
                           + (size_t)(((lane & 3) ^ ((lane >> 3) & 3)) * 4);

    // h0 = 0 (only hf[0] is read before first write)
    if (threadIdx.x < 64)
        *reinterpret_cast<u32x4*>(&hf[0][threadIdx.x][0]) = u32x4{0u, 0u, 0u, 0u};

    asm volatile("s_waitcnt vmcnt(0)" ::: "memory");   // drain setup loads for exact counting
    __builtin_amdgcn_sched_barrier(0);

    // Batched stage: wave w loads steps TB+2w, TB+2w+1 fully (4 chunks each)
    // -> per-row bytes [TB*256 + w*512, +512) contiguous, back-to-back requests.
#define STAGE(TB) do {                                                         \
    _Pragma("unroll")                                                          \
    for (int s2 = 0; s2 < 2; ++s2) {                                           \
        const int st  = (TB) + 2 * wid + s2;                                   \
        const int sl8 = st & 7;                                                \
        const float* gp = gbase + st * F_IN;                                   \
        GLDS16(gp,      &xs[sl8][0]);                                          \
        GLDS16(gp + 16, &xs[sl8][256]);                                        \
        GLDS16(gp + 32, &xs[sl8][512]);                                        \
        GLDS16(gp + 48, &xs[sl8][768]);                                        \
    }                                                                          \
} while (0)

    // prologue: batches for steps 0-3 and 4-7
    STAGE(0);
    STAGE(4);
    asm volatile("s_waitcnt vmcnt(8) lgkmcnt(0)" ::: "memory");  // batch0 + hf zeros done
    __builtin_amdgcn_sched_barrier(0);
    __builtin_amdgcn_s_barrier();
    __builtin_amdgcn_sched_barrier(0);

    const int swz = (cl >> 1) & 3;
    const int c0  = ((g4 & 1) * 2)     ^ swz;
    const int c1  = ((g4 & 1) * 2 + 1) ^ swz;
    const int kA  = (g4 >> 1) * 256 + cl * 16;
    const int kB  = kA + 512;
    const f32x4 z4 = {0.f, 0.f, 0.f, 0.f};

    // h-publish slot: unit u = wid*16 + g4*4 + r -> hf row (2*wid + (g4>>1))*16 + cl, elems (g4&1)*4..+3
    const int tT = (2 * wid + (g4 >> 1)) * 16 + cl;
    const int e0 = (g4 & 1) * 4;

    float c_st[4] = {0.f, 0.f, 0.f, 0.f};

    // PH = 0,1,2: plain step. PH = 3: stage next batch + counted vmcnt wait.
#define STEP(TT, PH) do {                                                      \
    const int par = (TT) & 1;                                                  \
    const float* sl = &xs[(TT) & 7][0];                                        \
    f32x4 xr0 = *(const f32x4*)(sl + kA + c0 * 4);                             \
    f32x4 xr1 = *(const f32x4*)(sl + kA + c1 * 4);                             \
    f32x4 xr2 = *(const f32x4*)(sl + kB + c0 * 4);                             \
    f32x4 xr3 = *(const f32x4*)(sl + kB + c1 * 4);                             \
    bf16x8 ah = *reinterpret_cast<const bf16x8*>(&hf[par][lane][0]);           \
    bf16x8 ax0, ax1;                                                           \
    _Pragma("unroll")                                                          \
    for (int j = 0; j < 4; ++j) {                                              \
        ax0[j]     = (__bf16)xr0[j];                                           \
        ax0[4 + j] = (__bf16)xr1[j];                                           \
        ax1[j]     = (__bf16)xr2[j];                                           \
        ax1[4 + j] = (__bf16)xr3[j];                                           \
    }                                                                          \
    f32x4 acc[4];                                                              \
    __builtin_amdgcn_s_setprio(1);                                             \
    _Pragma("unroll")                                                          \
    for (int qi = 0; qi < 4; ++qi) {                                           \
        f32x4 a = __builtin_amdgcn_mfma_f32_16x16x32_bf16(wfrag[0][qi], ax0, z4, 0, 0, 0); \
        a = __builtin_amdgcn_mfma_f32_16x16x32_bf16(wfrag[1][qi], ax1, a, 0, 0, 0);        \
        a = __builtin_amdgcn_mfma_f32_16x16x32_bf16(wfrag[2][qi], ah,  a, 0, 0, 0);        \
        acc[qi] = a;                                                           \
    }                                                                          \
    __builtin_amdgcn_s_setprio(0);                                             \
    float hh[4];                                                               \
    _Pragma("unroll")                                                          \
    for (int r = 0; r < 4; ++r) {                                              \
        float I  = __builtin_amdgcn_exp2f(__builtin_fmaf(acc[0][r], -L2E,        KI[r])); \
        float J  = __builtin_amdgcn_exp2f(__builtin_fmaf(acc[1][r], -2.0f * L2E, KJ[r])); \
        float P  = (1.0f - J) * __builtin_amdgcn_rcpf((1.0f + I) * (1.0f + J)); \
        float Fv = __builtin_amdgcn_exp2f(__builtin_fmaf(acc[2][r], -L2E,        KF[r])); \
        float S  = __builtin_amdgcn_rcpf(1.0f + Fv);                           \
        float cn = __builtin_fmaf(c_st[r], S, P);                              \
        float C  = __builtin_amdgcn_exp2f(-2.0f * L2E * cn);                   \
        float O  = __builtin_amdgcn_exp2f(__builtin_fmaf(acc[3][r], -L2E,      KO[r])); \
        hh[r] = (1.0f - C) * __builtin_amdgcn_rcpf((1.0f + C) * (1.0f + O));   \
        c_st[r] = cn;                                                          \
    }                                                                          \
    *reinterpret_cast<u32x2*>(&hf[par ^ 1][tT][e0]) =                          \
        u32x2{pk2(hh[0], hh[1]), pk2(hh[2], hh[3])};                           \
    if ((PH) == 3) {                                                           \
        if ((TT) + 5 < T_STEPS) {                                              \
            STAGE((TT) + 5);                                                   \
            asm volatile("s_waitcnt vmcnt(8) lgkmcnt(0)" ::: "memory");        \
        } else {                                                               \
            asm volatile("s_waitcnt vmcnt(0) lgkmcnt(0)" ::: "memory");        \
        }                                                                      \
    } else {                                                                   \
        asm volatile("s_waitcnt lgkmcnt(0)" ::: "memory");                     \
    }                                                                          \
    __builtin_amdgcn_sched_barrier(0);                                         \
    __builtin_amdgcn_s_barrier();                                              \
    __builtin_amdgcn_sched_barrier(0);                                         \
} while (0)

    for (int t = 0; t < T_STEPS; t += 4) {
        STEP(t,     0);
        STEP(t + 1, 1);
        STEP(t + 2, 2);
        STEP(t + 3, 3);
    }
#undef STEP
#undef STAGE

    // ---- epilogue: out[b] = ELU(sum_u h[u]*Wd[u] + bd) ----
    // T_STEPS even -> final h is in hf[0]; published by the loop's last barrier.
    if (wid == 0) {
        bf16x8 hfin = *reinterpret_cast<const bf16x8*>(&hf[0][lane][0]);
        float v = 0.f;
#pragma unroll
        for (int j = 0; j < 4; ++j) {
            v = __builtin_fmaf((float)hfin[j],     wdA[j], v);
            v = __builtin_fmaf((float)hfin[4 + j], wdB[j], v);
        }
        v += __shfl_xor(v, 16, 64);
        v += __shfl_xor(v, 32, 64);
        if (lane < 16) {
            float z = v + bd0;
            out[rowBase + lane] = z > 0.f ? z : (__expf(z) - 1.0f);
        }
    }
}

extern "C" void kernel_launch(void* const* d_in, const int* in_sizes, int n_in,
                              void* d_out, int out_size, void* d_ws, size_t ws_size,
                              hipStream_t stream) {
    const float* x  = (const float*)d_in[0];
    const float* Wl = (const float*)d_in[1];
    const float* bl = (const float*)d_in[2];
    const float* Wd = (const float*)d_in[3];
    const float* bd = (const float*)d_in[4];
    float* out = (float*)d_out;

    const int rows = out_size;              // B = 16384
    const int grid = (rows + 15) / 16;      // 16 rows per 128-thread block (2 waves/tile)
    hipLaunchKernelGGL(lstm_fused, dim3(grid), dim3(128), 0, stream,
                       x, Wl, bl, Wd, bd, out);
}